// Round 1
// baseline (4340.377 us; speedup 1.0000x reference)
//
#include <hip/hip_runtime.h>
#include <math.h>

#define NS 10000
#define LSEQ 32
#define DDIM 300
#define HDIM 300
#define BB 256
#define NMAX 128
#define MMAX 128
#define EPSR 0.1f
#define SITERS 50

// ---------------- K1: embedding + masked mean pool -> enc [NS, D] ----------
__global__ __launch_bounds__(320) void k_embed(const int* __restrict__ data,
                                               const float* __restrict__ emb,
                                               float* __restrict__ enc) {
  __shared__ int ids[LSEQ];
  int s = blockIdx.x;
  int tid = threadIdx.x;
  if (tid < LSEQ) ids[tid] = data[s * LSEQ + tid];
  __syncthreads();
  int cnt = 0;
  float acc = 0.f;
#pragma unroll
  for (int t = 0; t < LSEQ; ++t) {
    int id = ids[t];
    if (id != 0) {
      ++cnt;
      if (tid < DDIM) acc += emb[(size_t)id * DDIM + tid];
    }
  }
  if (tid < DDIM)
    enc[(size_t)s * DDIM + tid] = acc / (float)(cnt > 0 ? cnt : 1);
}

// ---------------- K2: generic tiled f32 GEMM + bias + relu -----------------
__global__ __launch_bounds__(256) void k_gemm_bias_relu(
    const float* __restrict__ A, const float* __restrict__ W,
    const float* __restrict__ bias, float* __restrict__ C,
    int M, int N, int K) {
  __shared__ float As[16][65];
  __shared__ float Ws[16][65];
  int tid = threadIdx.x;
  int tx = tid & 15, ty = tid >> 4;
  int m0 = blockIdx.x * 64, n0 = blockIdx.y * 64;
  float acc[4][4] = {};
  for (int k0 = 0; k0 < K; k0 += 16) {
    for (int l = tid; l < 1024; l += 256) {
      int kk = l & 15, mm = l >> 4;
      int m = m0 + mm, k = k0 + kk;
      As[kk][mm] = (m < M && k < K) ? A[(size_t)m * K + k] : 0.f;
    }
    for (int l = tid; l < 1024; l += 256) {
      int nn = l & 63, kk = l >> 6;
      int n = n0 + nn, k = k0 + kk;
      Ws[kk][nn] = (n < N && k < K) ? W[(size_t)k * N + n] : 0.f;
    }
    __syncthreads();
#pragma unroll
    for (int kk = 0; kk < 16; ++kk) {
      float a[4], w[4];
#pragma unroll
      for (int i = 0; i < 4; ++i) a[i] = As[kk][ty * 4 + i];
#pragma unroll
      for (int j = 0; j < 4; ++j) w[j] = Ws[kk][tx * 4 + j];
#pragma unroll
      for (int i = 0; i < 4; ++i)
#pragma unroll
        for (int j = 0; j < 4; ++j) acc[i][j] += a[i] * w[j];
    }
    __syncthreads();
  }
#pragma unroll
  for (int i = 0; i < 4; ++i) {
    int m = m0 + ty * 4 + i;
    if (m >= M) continue;
#pragma unroll
    for (int j = 0; j < 4; ++j) {
      int n = n0 + tx * 4 + j;
      if (n >= N) continue;
      float v = acc[i][j] + bias[n];
      C[(size_t)m * N + n] = v > 0.f ? v : 0.f;
    }
  }
}

// ---------------- K3: gather henc rows, zero-pad, inverse norms ------------
__global__ __launch_bounds__(256) void k_gather(
    const float* __restrict__ henc, const int* __restrict__ idx,
    const int* __restrict__ len, float* __restrict__ dst,
    float* __restrict__ inv) {
  int b = blockIdx.x;
  int wave = threadIdx.x >> 6, lane = threadIdx.x & 63;
  int n = len[b];
  for (int i = wave; i < NMAX; i += 4) {
    float* out = dst + ((size_t)b * NMAX + i) * HDIM;
    if (i < n) {
      const float* src = henc + (size_t)idx[b * NMAX + i] * HDIM;
      float ss = 0.f;
      for (int d = lane; d < HDIM; d += 64) {
        float x = src[d];
        out[d] = x;
        ss += x * x;
      }
#pragma unroll
      for (int off = 32; off > 0; off >>= 1) ss += __shfl_down(ss, off, 64);
      if (lane == 0) inv[b * NMAX + i] = 1.f / (sqrtf(ss) + 1e-8f);
    } else {
      for (int d = lane; d < HDIM; d += 64) out[d] = 0.f;
      if (lane == 0) inv[b * NMAX + i] = 0.f;
    }
  }
}

// ---------------- K4: cosine cost -> Gibbs kernel K = exp(-C/eps) ----------
__global__ __launch_bounds__(256) void k_cost(
    const float* __restrict__ rows, const float* __restrict__ cols,
    const float* __restrict__ rinv, const float* __restrict__ cinv,
    const int* __restrict__ rlen, const int* __restrict__ clen,
    float* __restrict__ Kmat) {
  __shared__ __align__(16) float Rs[16][HDIM];
  __shared__ __align__(16) float Cs[16][HDIM];
  int b = blockIdx.x;
  int r0 = blockIdx.y * 16;
  int tid = threadIdx.x;
  int rl = rlen[b], cl = clen[b];
  for (int l = tid; l < 16 * HDIM; l += 256) {
    int i = l / HDIM, d = l % HDIM;
    Rs[i][d] = rows[((size_t)b * NMAX + r0 + i) * HDIM + d] * rinv[b * NMAX + r0 + i];
  }
  int nl = tid >> 4, ml = tid & 15;
  for (int c0 = 0; c0 < MMAX; c0 += 16) {
    __syncthreads();
    for (int l = tid; l < 16 * HDIM; l += 256) {
      int j = l / HDIM, d = l % HDIM;
      Cs[j][d] = cols[((size_t)b * MMAX + c0 + j) * HDIM + d] * cinv[b * MMAX + c0 + j];
    }
    __syncthreads();
    int n = r0 + nl, m = c0 + ml;
    float kv = 0.f;
    if (n < rl && m < cl) {
      float acc = 0.f;
      const float4* rp = (const float4*)Rs[nl];
      const float4* cp = (const float4*)Cs[ml];
#pragma unroll 5
      for (int q = 0; q < HDIM / 4; ++q) {
        float4 r = rp[q], c = cp[q];
        acc += r.x * c.x + r.y * c.y + r.z * c.z + r.w * c.w;
      }
      kv = expf((acc - 1.f) / EPSR);  // exp(-(1-cos)/eps)
    }
    Kmat[((size_t)b * NMAX + n) * MMAX + m] = kv;
  }
}

// ---------------- K5: Sinkhorn (scaling form), K in 64KB swizzled LDS ------
__global__ __launch_bounds__(128) void k_sinkhorn(
    const float* __restrict__ Kmat, const int* __restrict__ rlen,
    const int* __restrict__ clen, float* ubuf, float* vbuf) {
  __shared__ float Ks[NMAX * MMAX];  // exactly 64KB, swizzle (m+n)&127
  int b = blockIdx.x;
  int tid = threadIdx.x;
  int rl = rlen[b], cl = clen[b];
  const float* Kg = Kmat + (size_t)b * NMAX * MMAX;
  for (int l = tid; l < NMAX * MMAX; l += 128) {
    int n = l >> 7, m = l & 127;
    Ks[(n << 7) | ((m + n) & 127)] = Kg[l];
  }
  float* u = ubuf + b * NMAX;
  float* v = vbuf + b * MMAX;
  v[tid] = (tid < cl) ? 1.f : 0.f;
  float a = (tid < rl) ? 1.f / (float)rl : 0.f;
  float bm = (tid < cl) ? 1.f / (float)cl : 0.f;
  __syncthreads();
  for (int it = 0; it < SITERS; ++it) {
    float un = 0.f;
    if (tid < rl) {
      float s = 0.f;
      int base = tid << 7;
#pragma unroll 4
      for (int m = 0; m < cl; ++m) s += Ks[base | ((m + tid) & 127)] * v[m];
      un = a / s;
    }
    u[tid] = un;
    __syncthreads();
    float vm = 0.f;
    if (tid < cl) {
      float s = 0.f;
#pragma unroll 4
      for (int n = 0; n < rl; ++n) s += Ks[(n << 7) | ((tid + n) & 127)] * u[n];
      vm = bm / s;
    }
    v[tid] = vm;
    __syncthreads();
  }
}

// ------------- K6: attend P@cols + compare + masked sum -> cr [B,H] --------
#define BT 320
__global__ __launch_bounds__(BT) void k_compare_rows(
    const float* __restrict__ rows, const float* __restrict__ cols,
    const float* __restrict__ Kmat, const float* __restrict__ ubuf,
    const float* __restrict__ vbuf, const int* __restrict__ rlen,
    const int* __restrict__ clen, const float* __restrict__ Wc,
    const float* __restrict__ bc, float* __restrict__ cr) {
  __shared__ float kv[16][MMAX];
  __shared__ __align__(16) float cat[16][2 * HDIM];
  int b = blockIdx.x;
  int tid = threadIdx.x;
  int rl = rlen[b], cl = clen[b];
  const float* u = ubuf + b * NMAX;
  const float* v = vbuf + b * MMAX;
  float crj = 0.f;
  for (int n0 = 0; n0 < rl; n0 += 16) {
    int nt = min(16, rl - n0);
    for (int l = tid; l < nt * MMAX; l += BT) {
      int i = l >> 7, m = l & 127;
      kv[i][m] = (m < cl) ? Kmat[((size_t)b * NMAX + n0 + i) * MMAX + m] * v[m] : 0.f;
    }
    for (int l = tid; l < nt * HDIM; l += BT) {
      int i = l / HDIM, d = l % HDIM;
      cat[i][d] = rows[((size_t)b * NMAX + n0 + i) * HDIM + d];
    }
    __syncthreads();
    // attended_col[i][d] = u[n0+i] * sum_m kv[i][m] * cols[m][d]
    for (int l = tid; l < nt * (HDIM / 4); l += BT) {
      int i = l / (HDIM / 4), q = l % (HDIM / 4);
      float sx = 0.f, sy = 0.f, sz = 0.f, sw = 0.f;
      for (int m = 0; m < cl; ++m) {
        float kvv = kv[i][m];
        float4 c = *((const float4*)(cols + ((size_t)b * MMAX + m) * HDIM) + q);
        sx += kvv * c.x; sy += kvv * c.y; sz += kvv * c.z; sw += kvv * c.w;
      }
      float uu = u[n0 + i];
      float4* dst4 = (float4*)&cat[i][HDIM] + q;
      *dst4 = make_float4(uu * sx, uu * sy, uu * sz, uu * sw);
    }
    __syncthreads();
    if (tid < HDIM) {
      float yacc[16];
      float bj = bc[tid];
#pragma unroll
      for (int i = 0; i < 16; ++i) yacc[i] = bj;
      for (int k4 = 0; k4 < 2 * HDIM; k4 += 4) {
        float w0 = Wc[(size_t)(k4 + 0) * HDIM + tid];
        float w1 = Wc[(size_t)(k4 + 1) * HDIM + tid];
        float w2 = Wc[(size_t)(k4 + 2) * HDIM + tid];
        float w3 = Wc[(size_t)(k4 + 3) * HDIM + tid];
        for (int i = 0; i < nt; ++i) {
          float4 c = *(const float4*)&cat[i][k4];
          yacc[i] += c.x * w0 + c.y * w1 + c.z * w2 + c.w * w3;
        }
      }
      for (int i = 0; i < nt; ++i) crj += yacc[i] > 0.f ? yacc[i] : 0.f;
    }
    __syncthreads();
  }
  if (tid < HDIM) cr[(size_t)b * HDIM + tid] = crj;
}

// ------------- K7: attend P^T@rows + compare + masked sum -> cc [B,H] ------
__global__ __launch_bounds__(BT) void k_compare_cols(
    const float* __restrict__ rows, const float* __restrict__ cols,
    const float* __restrict__ Kmat, const float* __restrict__ ubuf,
    const float* __restrict__ vbuf, const int* __restrict__ rlen,
    const int* __restrict__ clen, const float* __restrict__ Wc,
    const float* __restrict__ bc, float* __restrict__ cc) {
  __shared__ float ku[16][NMAX + 1];  // +1: break 128-stride bank conflicts
  __shared__ __align__(16) float cat[16][2 * HDIM];
  int b = blockIdx.x;
  int tid = threadIdx.x;
  int rl = rlen[b], cl = clen[b];
  const float* u = ubuf + b * NMAX;
  const float* v = vbuf + b * MMAX;
  float ccj = 0.f;
  for (int m0 = 0; m0 < cl; m0 += 16) {
    int mt = min(16, cl - m0);
    for (int l = tid; l < NMAX * 16; l += BT) {
      int n = l >> 4, j = l & 15;
      if (j < mt)
        ku[j][n] = (n < rl) ? Kmat[((size_t)b * NMAX + n) * MMAX + m0 + j] * u[n] : 0.f;
    }
    for (int l = tid; l < mt * HDIM; l += BT) {
      int j = l / HDIM, d = l % HDIM;
      cat[j][d] = cols[((size_t)b * MMAX + m0 + j) * HDIM + d];
    }
    __syncthreads();
    // attended_row[j][d] = v[m0+j] * sum_n ku[j][n] * rows[n][d]
    for (int l = tid; l < mt * (HDIM / 4); l += BT) {
      int j = l / (HDIM / 4), q = l % (HDIM / 4);
      float sx = 0.f, sy = 0.f, sz = 0.f, sw = 0.f;
      for (int n = 0; n < rl; ++n) {
        float kuv = ku[j][n];
        float4 r = *((const float4*)(rows + ((size_t)b * NMAX + n) * HDIM) + q);
        sx += kuv * r.x; sy += kuv * r.y; sz += kuv * r.z; sw += kuv * r.w;
      }
      float vv = v[m0 + j];
      float4* dst4 = (float4*)&cat[j][HDIM] + q;
      *dst4 = make_float4(vv * sx, vv * sy, vv * sz, vv * sw);
    }
    __syncthreads();
    if (tid < HDIM) {
      float yacc[16];
      float bj = bc[tid];
#pragma unroll
      for (int i = 0; i < 16; ++i) yacc[i] = bj;
      for (int k4 = 0; k4 < 2 * HDIM; k4 += 4) {
        float w0 = Wc[(size_t)(k4 + 0) * HDIM + tid];
        float w1 = Wc[(size_t)(k4 + 1) * HDIM + tid];
        float w2 = Wc[(size_t)(k4 + 2) * HDIM + tid];
        float w3 = Wc[(size_t)(k4 + 3) * HDIM + tid];
        for (int i = 0; i < mt; ++i) {
          float4 c = *(const float4*)&cat[i][k4];
          yacc[i] += c.x * w0 + c.y * w1 + c.z * w2 + c.w * w3;
        }
      }
      for (int i = 0; i < mt; ++i) ccj += yacc[i] > 0.f ? yacc[i] : 0.f;
    }
    __syncthreads();
  }
  if (tid < HDIM) cc[(size_t)b * HDIM + tid] = ccj;
}

// ---------------- K8: classifier head -> out [B,2] -------------------------
__global__ __launch_bounds__(320) void k_cls(
    const float* __restrict__ cr, const float* __restrict__ cc,
    const float* __restrict__ Wcls, const float* __restrict__ bcls,
    const float* __restrict__ Wout, const float* __restrict__ bout,
    float* __restrict__ out) {
  __shared__ __align__(16) float cz[2 * HDIM];
  __shared__ float zz[HDIM];
  int b = blockIdx.x, tid = threadIdx.x;
  if (tid < HDIM) {
    cz[tid] = cr[(size_t)b * HDIM + tid];
    cz[HDIM + tid] = cc[(size_t)b * HDIM + tid];
  }
  __syncthreads();
  if (tid < HDIM) {
    float acc = bcls[tid];
    for (int k4 = 0; k4 < 2 * HDIM; k4 += 4) {
      float4 c = *(const float4*)&cz[k4];
      acc += c.x * Wcls[(size_t)(k4 + 0) * HDIM + tid] +
             c.y * Wcls[(size_t)(k4 + 1) * HDIM + tid] +
             c.z * Wcls[(size_t)(k4 + 2) * HDIM + tid] +
             c.w * Wcls[(size_t)(k4 + 3) * HDIM + tid];
    }
    zz[tid] = acc > 0.f ? acc : 0.f;
  }
  __syncthreads();
  int o = tid >> 6, lane = tid & 63;
  if (o < 2) {
    float p = 0.f;
    for (int j = lane; j < HDIM; j += 64) p += zz[j] * Wout[(size_t)j * 2 + o];
#pragma unroll
    for (int off = 32; off > 0; off >>= 1) p += __shfl_down(p, off, 64);
    if (lane == 0) out[b * 2 + o] = p + bout[o];
  }
}

extern "C" void kernel_launch(void* const* d_in, const int* in_sizes, int n_in,
                              void* d_out, int out_size, void* d_ws, size_t ws_size,
                              hipStream_t stream) {
  (void)in_sizes; (void)n_in; (void)out_size; (void)ws_size;
  const int* data = (const int*)d_in[0];
  const int* row_idx = (const int*)d_in[1];
  const int* col_idx = (const int*)d_in[2];
  const int* row_len = (const int*)d_in[3];
  const int* col_len = (const int*)d_in[4];
  const float* emb = (const float*)d_in[5];
  const float* W1 = (const float*)d_in[6];
  const float* b1 = (const float*)d_in[7];
  const float* W2 = (const float*)d_in[8];
  const float* b2 = (const float*)d_in[9];
  const float* Wc = (const float*)d_in[10];
  const float* bc = (const float*)d_in[11];
  const float* Wcls = (const float*)d_in[12];
  const float* bcls = (const float*)d_in[13];
  const float* Wout = (const float*)d_in[14];
  const float* bout = (const float*)d_in[15];
  float* out = (float*)d_out;

  float* ws = (float*)d_ws;
  size_t off = 0;
  float* enc = ws + off; off += (size_t)NS * DDIM;   // also reused as henc
  float* h1 = ws + off; off += (size_t)NS * HDIM;
  float* rows = ws + off; off += (size_t)BB * NMAX * HDIM;
  float* cols = ws + off; off += (size_t)BB * MMAX * HDIM;
  float* rinv = ws + off; off += BB * NMAX;
  float* cinv = ws + off; off += BB * MMAX;
  float* Km = ws + off; off += (size_t)BB * NMAX * MMAX;
  float* ub = ws + off; off += BB * NMAX;
  float* vb = ws + off; off += BB * MMAX;
  float* cr = ws + off; off += BB * HDIM;
  float* cc = ws + off; off += BB * HDIM;
  float* henc = enc;  // gemm2 writes over enc (dead after gemm1)

  k_embed<<<NS, 320, 0, stream>>>(data, emb, enc);
  dim3 g1((NS + 63) / 64, (HDIM + 63) / 64);
  k_gemm_bias_relu<<<g1, 256, 0, stream>>>(enc, W1, b1, h1, NS, HDIM, DDIM);
  k_gemm_bias_relu<<<g1, 256, 0, stream>>>(h1, W2, b2, henc, NS, HDIM, HDIM);
  k_gather<<<BB, 256, 0, stream>>>(henc, row_idx, row_len, rows, rinv);
  k_gather<<<BB, 256, 0, stream>>>(henc, col_idx, col_len, cols, cinv);
  k_cost<<<dim3(BB, NMAX / 16), 256, 0, stream>>>(rows, cols, rinv, cinv,
                                                  row_len, col_len, Km);
  k_sinkhorn<<<BB, 128, 0, stream>>>(Km, row_len, col_len, ub, vb);
  k_compare_rows<<<BB, BT, 0, stream>>>(rows, cols, Km, ub, vb, row_len,
                                        col_len, Wc, bc, cr);
  k_compare_cols<<<BB, BT, 0, stream>>>(rows, cols, Km, ub, vb, row_len,
                                        col_len, Wc, bc, cc);
  k_cls<<<BB, 320, 0, stream>>>(cr, cc, Wcls, bcls, Wout, bout, out);
}

// Round 2
// 1039.744 us; speedup vs baseline: 4.1745x; 4.1745x over previous
//
#include <hip/hip_runtime.h>
#include <math.h>

#define NS 10000
#define LSEQ 32
#define DDIM 300
#define HDIM 300
#define BB 256
#define NMAX 128
#define MMAX 128
#define EPSR 0.1f
#define SITERS 50

// ---------------- K1: embedding + masked mean pool -> enc [NS, D] ----------
__global__ __launch_bounds__(320) void k_embed(const int* __restrict__ data,
                                               const float* __restrict__ emb,
                                               float* __restrict__ enc) {
  __shared__ int ids[LSEQ];
  int s = blockIdx.x;
  int tid = threadIdx.x;
  if (tid < LSEQ) ids[tid] = data[s * LSEQ + tid];
  __syncthreads();
  int cnt = 0;
  float acc = 0.f;
#pragma unroll
  for (int t = 0; t < LSEQ; ++t) {
    int id = ids[t];
    if (id != 0) {
      ++cnt;
      if (tid < DDIM) acc += emb[(size_t)id * DDIM + tid];
    }
  }
  if (tid < DDIM)
    enc[(size_t)s * DDIM + tid] = acc / (float)(cnt > 0 ? cnt : 1);
}

// ------------- K2: tiled f32 GEMM, optional bias+relu, float4 LDS ----------
__global__ __launch_bounds__(256) void k_gemm(
    const float* __restrict__ A, const float* __restrict__ W,
    const float* __restrict__ bias, float* __restrict__ C,
    int M, int N, int K, int relu) {
  __shared__ __align__(16) float As[16][68];
  __shared__ __align__(16) float Ws[16][68];
  int tid = threadIdx.x, tx = tid & 15, ty = tid >> 4;
  int m0 = blockIdx.x * 64, n0 = blockIdx.y * 64;
  float acc[4][4] = {};
  for (int k0 = 0; k0 < K; k0 += 16) {
    for (int l = tid; l < 1024; l += 256) {
      int kk = l & 15, mm = l >> 4;
      int m = m0 + mm, k = k0 + kk;
      As[kk][mm] = (m < M && k < K) ? A[(size_t)m * K + k] : 0.f;
    }
    for (int l = tid; l < 1024; l += 256) {
      int nn = l & 63, kk = l >> 6;
      int n = n0 + nn, k = k0 + kk;
      Ws[kk][nn] = (n < N && k < K) ? W[(size_t)k * N + n] : 0.f;
    }
    __syncthreads();
#pragma unroll
    for (int kk = 0; kk < 16; ++kk) {
      float4 av = *(const float4*)&As[kk][ty * 4];
      float4 wv = *(const float4*)&Ws[kk][tx * 4];
      float a[4] = {av.x, av.y, av.z, av.w};
      float w[4] = {wv.x, wv.y, wv.z, wv.w};
#pragma unroll
      for (int i = 0; i < 4; ++i)
#pragma unroll
        for (int j = 0; j < 4; ++j) acc[i][j] += a[i] * w[j];
    }
    __syncthreads();
  }
#pragma unroll
  for (int i = 0; i < 4; ++i) {
    int m = m0 + ty * 4 + i;
    if (m >= M) continue;
#pragma unroll
    for (int j = 0; j < 4; ++j) {
      int n = n0 + tx * 4 + j;
      if (n >= N) continue;
      float v = acc[i][j] + (bias ? bias[n] : 0.f);
      if (relu) v = v > 0.f ? v : 0.f;
      C[(size_t)m * N + n] = v;
    }
  }
}

// ---------------- K3: row-normalize henc -> hn [NS, H] ---------------------
__global__ __launch_bounds__(256) void k_norm(const float* __restrict__ henc,
                                              float* __restrict__ hn) {
  int s = blockIdx.x * 4 + (threadIdx.x >> 6);
  int lane = threadIdx.x & 63;
  if (s >= NS) return;
  const float* src = henc + (size_t)s * HDIM;
  float v[5];
  float ss = 0.f;
#pragma unroll
  for (int q = 0; q < 5; ++q) {
    int d = lane + q * 64;
    v[q] = (d < HDIM) ? src[d] : 0.f;
    ss += v[q] * v[q];
  }
#pragma unroll
  for (int off = 32; off > 0; off >>= 1) ss += __shfl_down(ss, off, 64);
  ss = __shfl(ss, 0, 64);
  float inv = 1.f / (sqrtf(ss) + 1e-8f);
  float* dst = hn + (size_t)s * HDIM;
#pragma unroll
  for (int q = 0; q < 5; ++q) {
    int d = lane + q * 64;
    if (d < HDIM) dst[d] = v[q] * inv;
  }
}

// ------------- K4: cosine cost via index gather -> K = exp(-C/eps) ---------
__global__ __launch_bounds__(256) void k_cost_idx(
    const float* __restrict__ hn, const int* __restrict__ ridx,
    const int* __restrict__ cidx, const int* __restrict__ rlen,
    const int* __restrict__ clen, float* __restrict__ Kmat) {
  __shared__ __align__(16) float Rs[16][HDIM];
  __shared__ __align__(16) float Cs[16][HDIM];
  int b = blockIdx.x;
  int r0 = blockIdx.y * 16;
  int tid = threadIdx.x;
  int rl = rlen[b], cl = clen[b];
  for (int l = tid; l < 16 * HDIM; l += 256) {
    int i = l / HDIM, d = l % HDIM;
    Rs[i][d] = hn[(size_t)ridx[b * NMAX + r0 + i] * HDIM + d];
  }
  int nl = tid >> 4, ml = tid & 15;
  for (int c0 = 0; c0 < MMAX; c0 += 16) {
    __syncthreads();
    for (int l = tid; l < 16 * HDIM; l += 256) {
      int j = l / HDIM, d = l % HDIM;
      Cs[j][d] = hn[(size_t)cidx[b * MMAX + c0 + j] * HDIM + d];
    }
    __syncthreads();
    int n = r0 + nl, m = c0 + ml;
    float kv = 0.f;
    if (n < rl && m < cl) {
      float acc = 0.f;
      const float4* rp = (const float4*)Rs[nl];
      const float4* cp = (const float4*)Cs[ml];
#pragma unroll 5
      for (int q = 0; q < HDIM / 4; ++q) {
        float4 r = rp[q], c = cp[q];
        acc += r.x * c.x + r.y * c.y + r.z * c.z + r.w * c.w;
      }
      kv = expf((acc - 1.f) / EPSR);  // exp(-(1-cos)/eps)
    }
    Kmat[((size_t)b * NMAX + n) * MMAX + m] = kv;
  }
}

// --------- K5: Sinkhorn (scaling form, u/v in LDS) + fused P write ---------
__global__ __launch_bounds__(128) void k_sinkhorn(
    float* __restrict__ Kmat, const int* __restrict__ rlen,
    const int* __restrict__ clen) {
  __shared__ float Ks[NMAX * MMAX];  // 64KB, swizzle (m+n)&127
  __shared__ float us[NMAX];
  __shared__ float vs[MMAX];
  int b = blockIdx.x;
  int tid = threadIdx.x;
  int rl = rlen[b], cl = clen[b];
  float* Kg = Kmat + (size_t)b * NMAX * MMAX;
  for (int l = tid; l < NMAX * MMAX; l += 128) {
    int n = l >> 7, m = l & 127;
    Ks[(n << 7) | ((m + n) & 127)] = Kg[l];
  }
  vs[tid] = (tid < cl) ? 1.f : 0.f;
  float a = (tid < rl) ? 1.f / (float)rl : 0.f;
  float bm = (tid < cl) ? 1.f / (float)cl : 0.f;
  __syncthreads();
  for (int it = 0; it < SITERS; ++it) {
    float un = 0.f;
    if (tid < rl) {
      float s = 0.f;
      int base = tid << 7;
#pragma unroll 4
      for (int m = 0; m < cl; ++m) s += Ks[base | ((m + tid) & 127)] * vs[m];
      un = a / s;
    }
    __syncthreads();
    us[tid] = un;
    __syncthreads();
    float vm = 0.f;
    if (tid < cl) {
      float s = 0.f;
#pragma unroll 4
      for (int n = 0; n < rl; ++n) s += Ks[(n << 7) | ((tid + n) & 127)] * us[n];
      vm = bm / s;
    }
    __syncthreads();
    vs[tid] = vm;
    __syncthreads();
  }
  // P = diag(u) K diag(v), written in place over Kmat
  for (int l = tid; l < NMAX * MMAX; l += 128) {
    int n = l >> 7, m = l & 127;
    Kg[l] = us[n] * Ks[(n << 7) | ((m + n) & 127)] * vs[m];
  }
}

// ---------------- K6: zero-init accumulator buffers ------------------------
__global__ void k_zero(float* __restrict__ p, int n) {
  int i = blockIdx.x * 256 + threadIdx.x;
  if (i < n) p[i] = 0.f;
}

// ------ K7: attend (P @ Hcb[idx]) + Hc[idx] + bc, relu, masked sum ---------
// SIDE 0: main=rows, P[i][k];  SIDE 1: main=cols, P[k][j] (transposed access)
template <int SIDE>
__global__ __launch_bounds__(256) void k_att_cmp(
    const float* __restrict__ P, const float* __restrict__ Hc,
    const float* __restrict__ Hcb, const int* __restrict__ idx_main,
    const int* __restrict__ idx_other, const int* __restrict__ len_main,
    const int* __restrict__ len_other, const float* __restrict__ bc,
    float* __restrict__ outacc) {
  int b = blockIdx.y;
  int lm = len_main[b], lo = len_other[b];
  int m0 = blockIdx.x * 64;
  if (m0 >= lm) return;
  int c0 = blockIdx.z * 64;
  __shared__ __align__(16) float Ps[16][68];
  __shared__ __align__(16) float Gs[16][68];
  int tid = threadIdx.x, tx = tid & 15, ty = tid >> 4;
  float acc[4][4] = {};
  const float* Pb = P + (size_t)b * NMAX * MMAX;
  int nch = (lo + 15) >> 4;
  for (int kc = 0; kc < nch; ++kc) {
    int k0 = kc << 4;
    if (SIDE == 0) {
      for (int l = tid; l < 1024; l += 256) {
        int kk = l & 15, mm = l >> 4;
        Ps[kk][mm] = Pb[(size_t)(m0 + mm) * MMAX + k0 + kk];
      }
    } else {
      for (int l = tid; l < 1024; l += 256) {
        int mm = l & 63, kk = l >> 6;
        Ps[kk][mm] = Pb[(size_t)(k0 + kk) * MMAX + m0 + mm];
      }
    }
    for (int l = tid; l < 1024; l += 256) {
      int jj = l & 63, kk = l >> 6;
      int col = c0 + jj;
      int row = idx_other[b * NMAX + k0 + kk];
      Gs[kk][jj] = (col < HDIM) ? Hcb[(size_t)row * HDIM + col] : 0.f;
    }
    __syncthreads();
#pragma unroll
    for (int kk = 0; kk < 16; ++kk) {
      float4 av = *(const float4*)&Ps[kk][ty * 4];
      float4 gv = *(const float4*)&Gs[kk][tx * 4];
      float a[4] = {av.x, av.y, av.z, av.w};
      float g[4] = {gv.x, gv.y, gv.z, gv.w};
#pragma unroll
      for (int i = 0; i < 4; ++i)
#pragma unroll
        for (int j = 0; j < 4; ++j) acc[i][j] += a[i] * g[j];
    }
    __syncthreads();
  }
  // epilogue: + Hc[idx_main] + bc, relu, masked row-sum, atomic col add
  float colsum[4] = {0.f, 0.f, 0.f, 0.f};
#pragma unroll
  for (int i = 0; i < 4; ++i) {
    int mi = m0 + ty * 4 + i;
    if (mi >= lm) continue;
    int hrow = idx_main[b * NMAX + mi];
#pragma unroll
    for (int j = 0; j < 4; ++j) {
      int col = c0 + tx * 4 + j;
      if (col >= HDIM) continue;
      float y = acc[i][j] + Hc[(size_t)hrow * HDIM + col] + bc[col];
      colsum[j] += y > 0.f ? y : 0.f;
    }
  }
  float(*red)[68] = Ps;  // reuse (synced at loop end)
#pragma unroll
  for (int j = 0; j < 4; ++j) red[ty][tx * 4 + j] = colsum[j];
  __syncthreads();
  if (tid < 64) {
    float s = 0.f;
#pragma unroll
    for (int r = 0; r < 16; ++r) s += red[r][tid];
    int col = c0 + tid;
    if (col < HDIM) atomicAdd(&outacc[(size_t)b * HDIM + col], s);
  }
}

// ---------------- K8: classifier head -> out [B,2] -------------------------
__global__ __launch_bounds__(320) void k_cls(
    const float* __restrict__ cr, const float* __restrict__ cc,
    const float* __restrict__ Wcls, const float* __restrict__ bcls,
    const float* __restrict__ Wout, const float* __restrict__ bout,
    float* __restrict__ out) {
  __shared__ __align__(16) float cz[2 * HDIM];
  __shared__ float zz[HDIM];
  int b = blockIdx.x, tid = threadIdx.x;
  if (tid < HDIM) {
    cz[tid] = cr[(size_t)b * HDIM + tid];
    cz[HDIM + tid] = cc[(size_t)b * HDIM + tid];
  }
  __syncthreads();
  if (tid < HDIM) {
    float acc = bcls[tid];
    for (int k4 = 0; k4 < 2 * HDIM; k4 += 4) {
      float4 c = *(const float4*)&cz[k4];
      acc += c.x * Wcls[(size_t)(k4 + 0) * HDIM + tid] +
             c.y * Wcls[(size_t)(k4 + 1) * HDIM + tid] +
             c.z * Wcls[(size_t)(k4 + 2) * HDIM + tid] +
             c.w * Wcls[(size_t)(k4 + 3) * HDIM + tid];
    }
    zz[tid] = acc > 0.f ? acc : 0.f;
  }
  __syncthreads();
  int o = tid >> 6, lane = tid & 63;
  if (o < 2) {
    float p = 0.f;
    for (int j = lane; j < HDIM; j += 64) p += zz[j] * Wout[(size_t)j * 2 + o];
#pragma unroll
    for (int off = 32; off > 0; off >>= 1) p += __shfl_down(p, off, 64);
    if (lane == 0) out[b * 2 + o] = p + bout[o];
  }
}

extern "C" void kernel_launch(void* const* d_in, const int* in_sizes, int n_in,
                              void* d_out, int out_size, void* d_ws, size_t ws_size,
                              hipStream_t stream) {
  (void)in_sizes; (void)n_in; (void)out_size; (void)ws_size;
  const int* data = (const int*)d_in[0];
  const int* row_idx = (const int*)d_in[1];
  const int* col_idx = (const int*)d_in[2];
  const int* row_len = (const int*)d_in[3];
  const int* col_len = (const int*)d_in[4];
  const float* emb = (const float*)d_in[5];
  const float* W1 = (const float*)d_in[6];
  const float* b1 = (const float*)d_in[7];
  const float* W2 = (const float*)d_in[8];
  const float* b2 = (const float*)d_in[9];
  const float* Wc = (const float*)d_in[10];
  const float* bc = (const float*)d_in[11];
  const float* Wcls = (const float*)d_in[12];
  const float* bcls = (const float*)d_in[13];
  const float* Wout = (const float*)d_in[14];
  const float* bout = (const float*)d_in[15];
  float* out = (float*)d_out;

  float* ws = (float*)d_ws;
  size_t off = 0;
  float* enc = ws + off; off += (size_t)NS * DDIM;
  float* h1 = ws + off; off += (size_t)NS * HDIM;
  float* henc = ws + off; off += (size_t)NS * HDIM;
  float* hn = ws + off; off += (size_t)NS * HDIM;
  float* Hc = ws + off; off += (size_t)NS * HDIM;
  float* Hcb = ws + off; off += (size_t)NS * HDIM;
  float* Km = ws + off; off += (size_t)BB * NMAX * MMAX;
  float* cr = ws + off; off += (size_t)BB * HDIM;
  float* cc = ws + off; off += (size_t)BB * HDIM;

  dim3 gNS((NS + 63) / 64, (HDIM + 63) / 64);

  k_embed<<<NS, 320, 0, stream>>>(data, emb, enc);
  k_gemm<<<gNS, 256, 0, stream>>>(enc, W1, b1, h1, NS, HDIM, DDIM, 1);
  k_gemm<<<gNS, 256, 0, stream>>>(h1, W2, b2, henc, NS, HDIM, HDIM, 1);
  k_norm<<<(NS + 3) / 4, 256, 0, stream>>>(henc, hn);
  k_gemm<<<gNS, 256, 0, stream>>>(henc, Wc, nullptr, Hc, NS, HDIM, HDIM, 0);
  k_gemm<<<gNS, 256, 0, stream>>>(henc, Wc + (size_t)HDIM * HDIM, nullptr, Hcb,
                                  NS, HDIM, HDIM, 0);
  k_cost_idx<<<dim3(BB, NMAX / 16), 256, 0, stream>>>(hn, row_idx, col_idx,
                                                      row_len, col_len, Km);
  k_sinkhorn<<<BB, 128, 0, stream>>>(Km, row_len, col_len);
  k_zero<<<(2 * BB * HDIM + 255) / 256, 256, 0, stream>>>(cr, 2 * BB * HDIM);
  k_att_cmp<0><<<dim3(NMAX / 64, BB, 5), 256, 0, stream>>>(
      Km, Hc, Hcb, row_idx, col_idx, row_len, col_len, bc, cr);
  k_att_cmp<1><<<dim3(MMAX / 64, BB, 5), 256, 0, stream>>>(
      Km, Hc, Hcb, col_idx, row_idx, col_len, row_len, bc, cc);
  k_cls<<<BB, 320, 0, stream>>>(cr, cc, Wcls, bcls, Wout, bout, out);
}

// Round 3
// 715.682 us; speedup vs baseline: 6.0647x; 1.4528x over previous
//
#include <hip/hip_runtime.h>
#include <math.h>

#define NS 10000
#define LSEQ 32
#define DDIM 300
#define HDIM 300
#define BB 256
#define NMAX 128
#define MMAX 128
#define EPSR 0.1f
#define SITERS 50

// ------- K1: embedding + masked mean pool -> enc [NS, D], float4 ----------
__global__ __launch_bounds__(256) void k_embed(const int* __restrict__ data,
                                               const float* __restrict__ emb,
                                               float* __restrict__ enc) {
  __shared__ int ids[LSEQ];
  __shared__ __align__(16) float4 part[3][76];
  int s = blockIdx.x;
  int tid = threadIdx.x;
  if (tid < LSEQ) ids[tid] = data[s * LSEQ + tid];
  __syncthreads();
  int cnt = 0;
#pragma unroll
  for (int t = 0; t < LSEQ; ++t) cnt += (ids[t] != 0) ? 1 : 0;
  int g = tid / 75, d = tid - g * 75;
  const float4* emb4 = (const float4*)emb;
  if (g < 3) {
    float4 acc = make_float4(0.f, 0.f, 0.f, 0.f);
    for (int t = g; t < LSEQ; t += 3) {
      int id = ids[t];
      if (id != 0) {
        float4 e = emb4[(size_t)id * 75 + d];
        acc.x += e.x; acc.y += e.y; acc.z += e.z; acc.w += e.w;
      }
    }
    part[g][d] = acc;
  }
  __syncthreads();
  if (g == 0) {
    float4 a = part[0][d], b = part[1][d], c = part[2][d];
    float inv = 1.f / (float)(cnt > 0 ? cnt : 1);
    float4 r = make_float4((a.x + b.x + c.x) * inv, (a.y + b.y + c.y) * inv,
                           (a.z + b.z + c.z) * inv, (a.w + b.w + c.w) * inv);
    ((float4*)enc)[(size_t)s * 75 + d] = r;
  }
}

// ------------- K2: tiled f32 GEMM, optional bias+relu, float4 LDS ----------
__global__ __launch_bounds__(256) void k_gemm(
    const float* __restrict__ A, const float* __restrict__ W,
    const float* __restrict__ bias, float* __restrict__ C,
    int M, int N, int K, int relu) {
  __shared__ __align__(16) float As[16][68];
  __shared__ __align__(16) float Ws[16][68];
  int tid = threadIdx.x, tx = tid & 15, ty = tid >> 4;
  int m0 = blockIdx.x * 64, n0 = blockIdx.y * 64;
  float acc[4][4] = {};
  for (int k0 = 0; k0 < K; k0 += 16) {
    for (int l = tid; l < 1024; l += 256) {
      int kk = l & 15, mm = l >> 4;
      int m = m0 + mm, k = k0 + kk;
      As[kk][mm] = (m < M && k < K) ? A[(size_t)m * K + k] : 0.f;
    }
    for (int l = tid; l < 1024; l += 256) {
      int nn = l & 63, kk = l >> 6;
      int n = n0 + nn, k = k0 + kk;
      Ws[kk][nn] = (n < N && k < K) ? W[(size_t)k * N + n] : 0.f;
    }
    __syncthreads();
#pragma unroll
    for (int kk = 0; kk < 16; ++kk) {
      float4 av = *(const float4*)&As[kk][ty * 4];
      float4 wv = *(const float4*)&Ws[kk][tx * 4];
      float a[4] = {av.x, av.y, av.z, av.w};
      float w[4] = {wv.x, wv.y, wv.z, wv.w};
#pragma unroll
      for (int i = 0; i < 4; ++i)
#pragma unroll
        for (int j = 0; j < 4; ++j) acc[i][j] += a[i] * w[j];
    }
    __syncthreads();
  }
#pragma unroll
  for (int i = 0; i < 4; ++i) {
    int m = m0 + ty * 4 + i;
    if (m >= M) continue;
#pragma unroll
    for (int j = 0; j < 4; ++j) {
      int n = n0 + tx * 4 + j;
      if (n >= N) continue;
      float v = acc[i][j] + (bias ? bias[n] : 0.f);
      if (relu) v = v > 0.f ? v : 0.f;
      C[(size_t)m * N + n] = v;
    }
  }
}

// ---------------- K3: row-normalize henc -> hn [NS, H] ---------------------
__global__ __launch_bounds__(256) void k_norm(const float* __restrict__ henc,
                                              float* __restrict__ hn) {
  int s = blockIdx.x * 4 + (threadIdx.x >> 6);
  int lane = threadIdx.x & 63;
  if (s >= NS) return;
  const float* src = henc + (size_t)s * HDIM;
  float v[5];
  float ss = 0.f;
#pragma unroll
  for (int q = 0; q < 5; ++q) {
    int d = lane + q * 64;
    v[q] = (d < HDIM) ? src[d] : 0.f;
    ss += v[q] * v[q];
  }
#pragma unroll
  for (int off = 32; off > 0; off >>= 1) ss += __shfl_down(ss, off, 64);
  ss = __shfl(ss, 0, 64);
  float inv = 1.f / (sqrtf(ss) + 1e-8f);
  float* dst = hn + (size_t)s * HDIM;
#pragma unroll
  for (int q = 0; q < 5; ++q) {
    int d = lane + q * 64;
    if (d < HDIM) dst[d] = v[q] * inv;
  }
}

// ------------- K4: cosine cost via index gather -> K = exp(-C/eps) ---------
__global__ __launch_bounds__(256) void k_cost_idx(
    const float* __restrict__ hn, const int* __restrict__ ridx,
    const int* __restrict__ cidx, const int* __restrict__ rlen,
    const int* __restrict__ clen, float* __restrict__ Kmat) {
  __shared__ __align__(16) float Rs[16][HDIM];
  __shared__ __align__(16) float Cs[16][HDIM];
  int b = blockIdx.x;
  int r0 = blockIdx.y * 16;
  int tid = threadIdx.x;
  int rl = rlen[b], cl = clen[b];
  for (int l = tid; l < 16 * HDIM; l += 256) {
    int i = l / HDIM, d = l % HDIM;
    Rs[i][d] = hn[(size_t)ridx[b * NMAX + r0 + i] * HDIM + d];
  }
  int nl = tid >> 4, ml = tid & 15;
  for (int c0 = 0; c0 < MMAX; c0 += 16) {
    __syncthreads();
    for (int l = tid; l < 16 * HDIM; l += 256) {
      int j = l / HDIM, d = l % HDIM;
      Cs[j][d] = hn[(size_t)cidx[b * MMAX + c0 + j] * HDIM + d];
    }
    __syncthreads();
    int n = r0 + nl, m = c0 + ml;
    float kv = 0.f;
    if (n < rl && m < cl) {
      float acc = 0.f;
      const float4* rp = (const float4*)Rs[nl];
      const float4* cp = (const float4*)Cs[ml];
#pragma unroll 5
      for (int q = 0; q < HDIM / 4; ++q) {
        float4 r = rp[q], c = cp[q];
        acc += r.x * c.x + r.y * c.y + r.z * c.z + r.w * c.w;
      }
      kv = expf((acc - 1.f) / EPSR);  // exp(-(1-cos)/eps)
    }
    Kmat[((size_t)b * NMAX + n) * MMAX + m] = kv;
  }
}

// --------- K5: Sinkhorn, K held in VGPRs (kr row / kt col slices) ----------
// 512 threads: n = tid>>2 (row/col id), q = tid&3 (quarter of the K range).
// u/v live in LDS, 4-way padded [4][36] so the 4-distinct-quad broadcast
// read pattern is bank-conflict-free. Quad partials reduce via shfl_xor.
__global__ __launch_bounds__(512) void k_sinkhorn(
    float* __restrict__ Kmat, const int* __restrict__ rlen,
    const int* __restrict__ clen) {
  __shared__ __align__(16) float vq[4][36];
  __shared__ __align__(16) float uq[4][36];
  int b = blockIdx.x;
  int tid = threadIdx.x;
  int n = tid >> 2, q = tid & 3;
  int rl = rlen[b], cl = clen[b];
  float* Kg = Kmat + (size_t)b * NMAX * MMAX;
  float kr[32], kt[32];
  const float4* Kg4 = (const float4*)(Kg + (size_t)n * MMAX + 32 * q);
#pragma unroll
  for (int t = 0; t < 8; ++t) *(float4*)&kr[4 * t] = Kg4[t];
#pragma unroll
  for (int j = 0; j < 32; ++j) kt[j] = Kg[(size_t)(32 * q + j) * MMAX + n];
  if (tid < 128) vq[tid >> 5][tid & 31] = (tid < cl) ? 1.f : 0.f;
  float av = (n < rl) ? 1.f / (float)rl : 0.f;
  float bv = (n < cl) ? 1.f / (float)cl : 0.f;
  float un = 0.f;
  __syncthreads();
  for (int it = 0; it < SITERS; ++it) {
    // ---- u-pass: s = sum_m K[n][m] v[m] (this thread: its 32-m slice) ----
    float s = 0.f;
#pragma unroll
    for (int t = 0; t < 8; ++t) {
      float4 vv = *(const float4*)&vq[q][4 * t];
      s += kr[4 * t + 0] * vv.x + kr[4 * t + 1] * vv.y +
           kr[4 * t + 2] * vv.z + kr[4 * t + 3] * vv.w;
    }
    s += __shfl_xor(s, 1, 64);
    s += __shfl_xor(s, 2, 64);
    un = (n < rl) ? av / s : 0.f;
    if (q == 0) uq[n >> 5][n & 31] = un;
    __syncthreads();
    // ---- v-pass: s2 = sum_n K[n][m] u[n] (this thread: its 32-n slice) ---
    float s2 = 0.f;
#pragma unroll
    for (int t = 0; t < 8; ++t) {
      float4 uu = *(const float4*)&uq[q][4 * t];
      s2 += kt[4 * t + 0] * uu.x + kt[4 * t + 1] * uu.y +
            kt[4 * t + 2] * uu.z + kt[4 * t + 3] * uu.w;
    }
    s2 += __shfl_xor(s2, 1, 64);
    s2 += __shfl_xor(s2, 2, 64);
    float vm = (n < cl) ? bv / s2 : 0.f;
    if (q == 0) vq[n >> 5][n & 31] = vm;
    __syncthreads();
  }
  // ---- fused P = diag(u) K diag(v), in place over Kmat ----
  float4* Pg4 = (float4*)(Kg + (size_t)n * MMAX + 32 * q);
#pragma unroll
  for (int t = 0; t < 8; ++t) {
    float4 vv = *(const float4*)&vq[q][4 * t];
    float4 p;
    p.x = un * kr[4 * t + 0] * vv.x;
    p.y = un * kr[4 * t + 1] * vv.y;
    p.z = un * kr[4 * t + 2] * vv.z;
    p.w = un * kr[4 * t + 3] * vv.w;
    Pg4[t] = p;
  }
}

// ---------------- K6: zero-init accumulator buffers ------------------------
__global__ void k_zero(float* __restrict__ p, int n) {
  int i = blockIdx.x * 256 + threadIdx.x;
  if (i < n) p[i] = 0.f;
}

// ------ K7: attend (P @ Hcb[idx]) + Hc[idx] + bc, relu, masked sum ---------
// SIDE 0: main=rows, P[i][k];  SIDE 1: main=cols, P[k][j] (transposed access)
template <int SIDE>
__global__ __launch_bounds__(256) void k_att_cmp(
    const float* __restrict__ P, const float* __restrict__ Hc,
    const float* __restrict__ Hcb, const int* __restrict__ idx_main,
    const int* __restrict__ idx_other, const int* __restrict__ len_main,
    const int* __restrict__ len_other, const float* __restrict__ bc,
    float* __restrict__ outacc) {
  int b = blockIdx.y;
  int lm = len_main[b], lo = len_other[b];
  int m0 = blockIdx.x * 64;
  if (m0 >= lm) return;
  int c0 = blockIdx.z * 64;
  __shared__ __align__(16) float Ps[16][68];
  __shared__ __align__(16) float Gs[16][68];
  int tid = threadIdx.x, tx = tid & 15, ty = tid >> 4;
  float acc[4][4] = {};
  const float* Pb = P + (size_t)b * NMAX * MMAX;
  int nch = (lo + 15) >> 4;
  for (int kc = 0; kc < nch; ++kc) {
    int k0 = kc << 4;
    if (SIDE == 0) {
      for (int l = tid; l < 1024; l += 256) {
        int kk = l & 15, mm = l >> 4;
        Ps[kk][mm] = Pb[(size_t)(m0 + mm) * MMAX + k0 + kk];
      }
    } else {
      for (int l = tid; l < 1024; l += 256) {
        int mm = l & 63, kk = l >> 6;
        Ps[kk][mm] = Pb[(size_t)(k0 + kk) * MMAX + m0 + mm];
      }
    }
    for (int l = tid; l < 1024; l += 256) {
      int jj = l & 63, kk = l >> 6;
      int col = c0 + jj;
      int row = idx_other[b * NMAX + k0 + kk];
      Gs[kk][jj] = (col < HDIM) ? Hcb[(size_t)row * HDIM + col] : 0.f;
    }
    __syncthreads();
#pragma unroll
    for (int kk = 0; kk < 16; ++kk) {
      float4 av = *(const float4*)&Ps[kk][ty * 4];
      float4 gv = *(const float4*)&Gs[kk][tx * 4];
      float a[4] = {av.x, av.y, av.z, av.w};
      float g[4] = {gv.x, gv.y, gv.z, gv.w};
#pragma unroll
      for (int i = 0; i < 4; ++i)
#pragma unroll
        for (int j = 0; j < 4; ++j) acc[i][j] += a[i] * g[j];
    }
    __syncthreads();
  }
  // epilogue: + Hc[idx_main] + bc, relu, masked row-sum, atomic col add
  float colsum[4] = {0.f, 0.f, 0.f, 0.f};
#pragma unroll
  for (int i = 0; i < 4; ++i) {
    int mi = m0 + ty * 4 + i;
    if (mi >= lm) continue;
    int hrow = idx_main[b * NMAX + mi];
#pragma unroll
    for (int j = 0; j < 4; ++j) {
      int col = c0 + tx * 4 + j;
      if (col >= HDIM) continue;
      float y = acc[i][j] + Hc[(size_t)hrow * HDIM + col] + bc[col];
      colsum[j] += y > 0.f ? y : 0.f;
    }
  }
  float(*red)[68] = Ps;  // reuse (synced at loop end)
#pragma unroll
  for (int j = 0; j < 4; ++j) red[ty][tx * 4 + j] = colsum[j];
  __syncthreads();
  if (tid < 64) {
    float s = 0.f;
#pragma unroll
    for (int r = 0; r < 16; ++r) s += red[r][tid];
    int col = c0 + tid;
    if (col < HDIM) atomicAdd(&outacc[(size_t)b * HDIM + col], s);
  }
}

// ---------------- K8: classifier head -> out [B,2] -------------------------
__global__ __launch_bounds__(320) void k_cls(
    const float* __restrict__ cr, const float* __restrict__ cc,
    const float* __restrict__ Wcls, const float* __restrict__ bcls,
    const float* __restrict__ Wout, const float* __restrict__ bout,
    float* __restrict__ out) {
  __shared__ __align__(16) float cz[2 * HDIM];
  __shared__ float zz[HDIM];
  int b = blockIdx.x, tid = threadIdx.x;
  if (tid < HDIM) {
    cz[tid] = cr[(size_t)b * HDIM + tid];
    cz[HDIM + tid] = cc[(size_t)b * HDIM + tid];
  }
  __syncthreads();
  if (tid < HDIM) {
    float acc = bcls[tid];
    for (int k4 = 0; k4 < 2 * HDIM; k4 += 4) {
      float4 c = *(const float4*)&cz[k4];
      acc += c.x * Wcls[(size_t)(k4 + 0) * HDIM + tid] +
             c.y * Wcls[(size_t)(k4 + 1) * HDIM + tid] +
             c.z * Wcls[(size_t)(k4 + 2) * HDIM + tid] +
             c.w * Wcls[(size_t)(k4 + 3) * HDIM + tid];
    }
    zz[tid] = acc > 0.f ? acc : 0.f;
  }
  __syncthreads();
  int o = tid >> 6, lane = tid & 63;
  if (o < 2) {
    float p = 0.f;
    for (int j = lane; j < HDIM; j += 64) p += zz[j] * Wout[(size_t)j * 2 + o];
#pragma unroll
    for (int off = 32; off > 0; off >>= 1) p += __shfl_down(p, off, 64);
    if (lane == 0) out[b * 2 + o] = p + bout[o];
  }
}

extern "C" void kernel_launch(void* const* d_in, const int* in_sizes, int n_in,
                              void* d_out, int out_size, void* d_ws, size_t ws_size,
                              hipStream_t stream) {
  (void)in_sizes; (void)n_in; (void)out_size; (void)ws_size;
  const int* data = (const int*)d_in[0];
  const int* row_idx = (const int*)d_in[1];
  const int* col_idx = (const int*)d_in[2];
  const int* row_len = (const int*)d_in[3];
  const int* col_len = (const int*)d_in[4];
  const float* emb = (const float*)d_in[5];
  const float* W1 = (const float*)d_in[6];
  const float* b1 = (const float*)d_in[7];
  const float* W2 = (const float*)d_in[8];
  const float* b2 = (const float*)d_in[9];
  const float* Wc = (const float*)d_in[10];
  const float* bc = (const float*)d_in[11];
  const float* Wcls = (const float*)d_in[12];
  const float* bcls = (const float*)d_in[13];
  const float* Wout = (const float*)d_in[14];
  const float* bout = (const float*)d_in[15];
  float* out = (float*)d_out;

  float* ws = (float*)d_ws;
  size_t off = 0;
  float* enc = ws + off; off += (size_t)NS * DDIM;
  float* h1 = ws + off; off += (size_t)NS * HDIM;
  float* henc = ws + off; off += (size_t)NS * HDIM;
  float* hn = ws + off; off += (size_t)NS * HDIM;
  float* Hc = ws + off; off += (size_t)NS * HDIM;
  float* Hcb = ws + off; off += (size_t)NS * HDIM;
  float* Km = ws + off; off += (size_t)BB * NMAX * MMAX;
  float* cr = ws + off; off += (size_t)BB * HDIM;
  float* cc = ws + off; off += (size_t)BB * HDIM;

  dim3 gNS((NS + 63) / 64, (HDIM + 63) / 64);

  k_embed<<<NS, 256, 0, stream>>>(data, emb, enc);
  k_gemm<<<gNS, 256, 0, stream>>>(enc, W1, b1, h1, NS, HDIM, DDIM, 1);
  k_gemm<<<gNS, 256, 0, stream>>>(h1, W2, b2, henc, NS, HDIM, HDIM, 1);
  k_norm<<<(NS + 3) / 4, 256, 0, stream>>>(henc, hn);
  k_gemm<<<gNS, 256, 0, stream>>>(henc, Wc, nullptr, Hc, NS, HDIM, HDIM, 0);
  k_gemm<<<gNS, 256, 0, stream>>>(henc, Wc + (size_t)HDIM * HDIM, nullptr, Hcb,
                                  NS, HDIM, HDIM, 0);
  k_cost_idx<<<dim3(BB, NMAX / 16), 256, 0, stream>>>(hn, row_idx, col_idx,
                                                      row_len, col_len, Km);
  k_sinkhorn<<<BB, 512, 0, stream>>>(Km, row_len, col_len);
  k_zero<<<(2 * BB * HDIM + 255) / 256, 256, 0, stream>>>(cr, 2 * BB * HDIM);
  k_att_cmp<0><<<dim3(NMAX / 64, BB, 5), 256, 0, stream>>>(
      Km, Hc, Hcb, row_idx, col_idx, row_len, col_len, bc, cr);
  k_att_cmp<1><<<dim3(MMAX / 64, BB, 5), 256, 0, stream>>>(
      Km, Hc, Hcb, col_idx, row_idx, col_len, row_len, bc, cc);
  k_cls<<<BB, 320, 0, stream>>>(cr, cc, Wcls, bcls, Wout, bout, out);
}